// Round 5
// baseline (276.612 us; speedup 1.0000x reference)
//
#include <hip/hip_runtime.h>

#define NN 50000
#define NE 800000
#define NBLK 196  // ceil(NN/256)

// ---------------- CSR build ----------------
__global__ void k_hist(const int* __restrict__ dst, int* __restrict__ deg) {
  int e = blockIdx.x * 256 + threadIdx.x;
  if (e < NE) atomicAdd(&deg[dst[e]], 1);
}

__global__ void k_blksum(const int* __restrict__ deg, int* __restrict__ blksum) {
  __shared__ int s[256];
  int n = blockIdx.x * 256 + threadIdx.x;
  s[threadIdx.x] = (n < NN) ? deg[n] : 0;
  __syncthreads();
  for (int off = 128; off > 0; off >>= 1) {
    if (threadIdx.x < off) s[threadIdx.x] += s[threadIdx.x + off];
    __syncthreads();
  }
  if (threadIdx.x == 0) blksum[blockIdx.x] = s[0];
}

__global__ void k_blkscan(const int* __restrict__ blksum, int* __restrict__ blkoff) {
  __shared__ int s[256];
  int t = threadIdx.x;
  int v0 = (t < NBLK) ? blksum[t] : 0;
  s[t] = v0;
  __syncthreads();
  for (int off = 1; off < 256; off <<= 1) {
    int v = (t >= off) ? s[t - off] : 0;
    __syncthreads();
    s[t] += v;
    __syncthreads();
  }
  if (t < NBLK) blkoff[t] = s[t] - v0;  // exclusive
}

__global__ void k_scan3(const int* __restrict__ deg, const int* __restrict__ blkoff,
                        int* __restrict__ row_start, int* __restrict__ cursor,
                        float* __restrict__ dinv) {
  __shared__ int s[256];
  int n = blockIdx.x * 256 + threadIdx.x;
  int d = (n < NN) ? deg[n] : 0;
  s[threadIdx.x] = d;
  __syncthreads();
  for (int off = 1; off < 256; off <<= 1) {
    int v = (threadIdx.x >= off) ? s[threadIdx.x - off] : 0;
    __syncthreads();
    s[threadIdx.x] += v;
    __syncthreads();
  }
  if (n < NN) {
    int rs = blkoff[blockIdx.x] + s[threadIdx.x] - d;
    row_start[n] = rs;
    cursor[n] = rs;
    dinv[n] = rsqrtf((float)d + 2.0f);
  }
  if (n == 0) row_start[NN] = NE;
}

__global__ void k_scatter(const int* __restrict__ srcv, const int* __restrict__ dstv,
                          const float* __restrict__ dinv, int* __restrict__ cursor,
                          int2* __restrict__ epk) {
  int e = blockIdx.x * 256 + threadIdx.x;
  if (e >= NE) return;
  int s = srcv[e], d = dstv[e];
  int pos = atomicAdd(&cursor[d], 1);
  epk[pos] = make_int2(s, __float_as_int(dinv[s] * dinv[d]));
}

// ---------------- weight composition (tiny) ----------------
__global__ void k_prep_misc(const float* __restrict__ w2, const float* __restrict__ fw2,
                            const float* __restrict__ w3, const float* __restrict__ fw3,
                            const float* __restrict__ b1, const float* __restrict__ fw1,
                            const float* __restrict__ fb1,
                            const float* __restrict__ b2, const float* __restrict__ fb2,
                            const float* __restrict__ b3, const float* __restrict__ fb3,
                            float* __restrict__ Wc2, float* __restrict__ Wc3,
                            float* __restrict__ bc1, float* __restrict__ bc2,
                            float* __restrict__ bc3) {
  int id = blockIdx.x * 256 + threadIdx.x;
  if (id < 2048) {                       // Wc2 [32,64]
    int c = id >> 6, k = id & 63;
    float s = 0.f;
    for (int j = 0; j < 64; ++j) s = fmaf(w2[c * 64 + j], fw2[j * 64 + k], s);
    Wc2[id] = s;
  } else if (id < 10240) {               // Wc3 [64,128]
    int idx = id - 2048;
    int c = idx >> 7, k = idx & 127;
    float s = 0.f;
    for (int j = 0; j < 128; ++j) s = fmaf(w3[c * 128 + j], fw3[j * 128 + k], s);
    Wc3[idx] = s;
  } else if (id < 10272) {               // bc1 [32]
    int k = id - 10240;
    float s = fb1[k];
    for (int j = 0; j < 32; ++j) s = fmaf(b1[j], fw1[j * 32 + k], s);
    bc1[k] = s;
  } else if (id < 10336) {               // bc2 [64]
    int k = id - 10272;
    float s = fb2[k];
    for (int j = 0; j < 64; ++j) s = fmaf(b2[j], fw2[j * 64 + k], s);
    bc2[k] = s;
  } else if (id < 10464) {               // bc3 [128]
    int k = id - 10336;
    float s = fb3[k];
    for (int j = 0; j < 128; ++j) s = fmaf(b3[j], fw3[j * 128 + k], s);
    bc3[k] = s;
  }
}

__global__ void k_prep_G(const float* __restrict__ wd3, const float* __restrict__ wf,
                         float* __restrict__ G) {
  int id = blockIdx.x * 256 + threadIdx.x;
  if (id >= 16384) return;
  int k = id & 127, r = id >> 7;
  int c = r >> 2, l = r & 3;
  float s = 0.f;
  for (int o = 0; o < 32; ++o) {
    s = fmaf(wd3[c * 64 + o * 2 + 0], wf[(o * 8 + 2 * l + 0) * 128 + k], s);
    s = fmaf(wd3[c * 64 + o * 2 + 1], wf[(o * 8 + 2 * l + 1) * 128 + k], s);
  }
  G[r * 128 + k] = s;
}

__global__ void k_prep_HA1(const float* __restrict__ wd2, const float* __restrict__ G,
                           const float* __restrict__ ws2,
                           float* __restrict__ Hm, float* __restrict__ A1) {
  int id = blockIdx.x * 256 + threadIdx.x;
  if (id < 16384) {
    int k = id & 127, r = id >> 7;
    int c = r >> 1, l = r & 1;
    float s = 0.f;
    for (int o = 0; o < 32; ++o) {
      s = fmaf(wd2[c * 64 + o * 2 + 0], G[(o * 4 + 2 * l + 0) * 128 + k], s);
      s = fmaf(wd2[c * 64 + o * 2 + 1], G[(o * 4 + 2 * l + 1) * 128 + k], s);
    }
    Hm[r * 128 + k] = s;
  } else if (id < 16384 + 4096) {
    int idx = id - 16384;
    int k = idx & 127, c = idx >> 7;   // c < 32
    float s = 0.f;
    for (int o = 0; o < 32; ++o) {
      float g = G[(4 * o) * 128 + k] + G[(4 * o + 1) * 128 + k] +
                G[(4 * o + 2) * 128 + k] + G[(4 * o + 3) * 128 + k];
      s = fmaf(ws2[c * 32 + o], g, s);
    }
    A1[c * 128 + k] = s;
  }
}

__global__ void k_prep_A32c0(const float* __restrict__ wd1, const float* __restrict__ ws1,
                             const float* __restrict__ Hm, const float* __restrict__ G,
                             const float* __restrict__ wf,
                             const float* __restrict__ bd1, const float* __restrict__ bs1,
                             const float* __restrict__ bd2, const float* __restrict__ bs2,
                             const float* __restrict__ bd3, const float* __restrict__ bf,
                             float* __restrict__ A3, float* __restrict__ A2,
                             float* __restrict__ c0) {
  int id = blockIdx.x * 256 + threadIdx.x;
  if (id < 16384) {
    int k = id & 127, c = id >> 7;
    float s = 0.f;
    for (int j = 0; j < 128; ++j) s = fmaf(wd1[c * 128 + j], Hm[j * 128 + k], s);
    A3[c * 128 + k] = s;
  } else if (id < 16384 + 8192) {
    int idx = id - 16384;
    int k = idx & 127, c = idx >> 7;   // c < 64
    float s = 0.f;
    for (int o = 0; o < 64; ++o)
      s = fmaf(ws1[c * 64 + o], Hm[(2 * o) * 128 + k] + Hm[(2 * o + 1) * 128 + k], s);
    A2[c * 128 + k] = s;
  } else if (id < 16384 + 8192 + 128) {
    int k = id - 16384 - 8192;
    float s = bf[k];
    for (int o = 0; o < 64; ++o) {
      float b = bd1[o] + bs1[o];
      s = fmaf(b, Hm[(o * 2) * 128 + k] + Hm[(o * 2 + 1) * 128 + k], s);
    }
    for (int o = 0; o < 32; ++o) {
      float b = bd2[o] + bs2[o];
      float g = G[(o * 4) * 128 + k] + G[(o * 4 + 1) * 128 + k] +
                G[(o * 4 + 2) * 128 + k] + G[(o * 4 + 3) * 128 + k];
      s = fmaf(b, g, s);
    }
    for (int o = 0; o < 32; ++o) {
      float w8 = 0.f;
      for (int j = 0; j < 8; ++j) w8 += wf[(o * 8 + j) * 128 + k];
      s = fmaf(bd3[o], w8, s);
    }
    c0[k] = s;
  }
}

// ---------------- layer-1 projection: h1 = x @ w1 (128->32), register-tiled ----------
__launch_bounds__(256)
__global__ void k_gemm1t(const float* __restrict__ X, const float* __restrict__ W,
                         float* __restrict__ Y) {
  __shared__ float sW[128 * 32];
  __shared__ float sXc[128 * 33];
  int t = threadIdx.x;
  int n0 = blockIdx.x * 128;
#pragma unroll
  for (int it = 0; it < 4; ++it) {          // stage full W (16 KB)
    int idx = t + it * 256;                  // 1024 float4 slots
    int kr = idx >> 3, c4 = (idx & 7) * 4;
    *reinterpret_cast<float4*>(&sW[kr * 32 + c4]) =
        *reinterpret_cast<const float4*>(&W[kr * 32 + c4]);
  }
  int rg = t >> 3;   // 0..31 -> rows 4rg..4rg+3
  int cg = t & 7;    // cols 4cg..4cg+3
  float acc[4][4];
#pragma unroll
  for (int r = 0; r < 4; ++r)
#pragma unroll
    for (int c = 0; c < 4; ++c) acc[r][c] = 0.f;

  for (int ch = 0; ch < 4; ++ch) {
    __syncthreads();
#pragma unroll
    for (int it = 0; it < 4; ++it) {        // stage X chunk [128 rows][32 k]
      int idx = t + it * 256;
      int row = idx & 127, k4 = (idx >> 7) * 4;
      int n = n0 + row;
      float4 v = make_float4(0.f, 0.f, 0.f, 0.f);
      if (n < NN) v = *reinterpret_cast<const float4*>(&X[(size_t)n * 128 + ch * 32 + k4]);
      sXc[row * 33 + k4 + 0] = v.x;
      sXc[row * 33 + k4 + 1] = v.y;
      sXc[row * 33 + k4 + 2] = v.z;
      sXc[row * 33 + k4 + 3] = v.w;
    }
    __syncthreads();
#pragma unroll
    for (int k = 0; k < 32; ++k) {
      float4 w = *reinterpret_cast<const float4*>(&sW[(ch * 32 + k) * 32 + cg * 4]);
#pragma unroll
      for (int r = 0; r < 4; ++r) {
        float xv = sXc[(rg * 4 + r) * 33 + k];
        acc[r][0] = fmaf(xv, w.x, acc[r][0]);
        acc[r][1] = fmaf(xv, w.y, acc[r][1]);
        acc[r][2] = fmaf(xv, w.z, acc[r][2]);
        acc[r][3] = fmaf(xv, w.w, acc[r][3]);
      }
    }
  }
#pragma unroll
  for (int r = 0; r < 4; ++r) {
    int n = n0 + rg * 4 + r;
    if (n < NN)
      *reinterpret_cast<float4*>(&Y[(size_t)n * 32 + cg * 4]) =
          make_float4(acc[r][0], acc[r][1], acc[r][2], acc[r][3]);
  }
}

// ---- 4-way gather core for F=32: 32 lanes/node (fg=lane&7, way=(lane>>3)&3) ----
__device__ inline float4 gather32_core(const float4* __restrict__ H4,
                                       const int2* __restrict__ epk,
                                       const int* __restrict__ row_start,
                                       const float* __restrict__ dinv,
                                       int n, int fg, int way) {
  float4 acc = make_float4(0.f, 0.f, 0.f, 0.f);
  if (way == 0) {
    float dv = dinv[n], s2 = 2.f * dv * dv;
    float4 h = H4[(size_t)n * 8 + fg];
    acc.x = s2 * h.x; acc.y = s2 * h.y; acc.z = s2 * h.z; acc.w = s2 * h.w;
  }
  int end = row_start[n + 1];
  int i = row_start[n] + way;
  for (; i + 4 < end; i += 8) {
    int2 p0 = epk[i], p1 = epk[i + 4];
    float c0f = __int_as_float(p0.y), c1f = __int_as_float(p1.y);
    float4 a = H4[(size_t)p0.x * 8 + fg];
    float4 b = H4[(size_t)p1.x * 8 + fg];
    acc.x = fmaf(c0f, a.x, acc.x); acc.y = fmaf(c0f, a.y, acc.y);
    acc.z = fmaf(c0f, a.z, acc.z); acc.w = fmaf(c0f, a.w, acc.w);
    acc.x = fmaf(c1f, b.x, acc.x); acc.y = fmaf(c1f, b.y, acc.y);
    acc.z = fmaf(c1f, b.z, acc.z); acc.w = fmaf(c1f, b.w, acc.w);
  }
  if (i < end) {
    int2 p = epk[i];
    float cf = __int_as_float(p.y);
    float4 a = H4[(size_t)p.x * 8 + fg];
    acc.x = fmaf(cf, a.x, acc.x); acc.y = fmaf(cf, a.y, acc.y);
    acc.z = fmaf(cf, a.z, acc.z); acc.w = fmaf(cf, a.w, acc.w);
  }
  // butterfly reduce over 4 ways (masks 8,16 within the 32-lane node group)
  acc.x += __shfl_xor(acc.x, 8);  acc.y += __shfl_xor(acc.y, 8);
  acc.z += __shfl_xor(acc.z, 8);  acc.w += __shfl_xor(acc.w, 8);
  acc.x += __shfl_xor(acc.x, 16); acc.y += __shfl_xor(acc.y, 16);
  acc.z += __shfl_xor(acc.z, 16); acc.w += __shfl_xor(acc.w, 16);
  return acc;
}

// ---------------- fused 4-way gather(F=32) + GEMM 32->32 + relu ----------------
// 8 nodes/block (32 lanes/node). NN % 8 == 0.
__launch_bounds__(256)
__global__ void k_fuse1(const float* __restrict__ H, const int2* __restrict__ epk,
                        const int* __restrict__ row_start, const float* __restrict__ dinv,
                        const float* __restrict__ W, const float* __restrict__ bias,
                        float* __restrict__ Y) {
  __shared__ float sZT[32][9];   // [feat][node]
  __shared__ float sW[32 * 32];
  int t = threadIdx.x;
  int n0 = blockIdx.x * 8;
  {  // stage W (4 KB)
    int kr = t >> 3, c4 = (t & 7) * 4;
    *reinterpret_cast<float4*>(&sW[kr * 32 + c4]) =
        *reinterpret_cast<const float4*>(&W[kr * 32 + c4]);
  }
  int node = t >> 5, fg = t & 7, way = (t >> 3) & 3;
  float4 z = gather32_core(reinterpret_cast<const float4*>(H), epk, row_start, dinv,
                           n0 + node, fg, way);
  if (way == 0) {
    sZT[fg * 4 + 0][node] = z.x;
    sZT[fg * 4 + 1][node] = z.y;
    sZT[fg * 4 + 2][node] = z.z;
    sZT[fg * 4 + 3][node] = z.w;
  }
  __syncthreads();
  int nd = t >> 5, col = t & 31;
  float a = bias[col];
#pragma unroll
  for (int k = 0; k < 32; ++k) a = fmaf(sZT[k][nd], sW[k * 32 + col], a);
  Y[(size_t)(n0 + nd) * 32 + col] = fmaxf(a, 0.f);
}

// ---------------- fused 4-way gather(F=32) + GEMM 32->64 + relu ----------------
__launch_bounds__(256)
__global__ void k_fuse2(const float* __restrict__ H, const int2* __restrict__ epk,
                        const int* __restrict__ row_start, const float* __restrict__ dinv,
                        const float* __restrict__ W, const float* __restrict__ bias,
                        float* __restrict__ Y) {
  __shared__ float sZT[32][9];
  __shared__ float sW[32 * 64];
  int t = threadIdx.x;
  int n0 = blockIdx.x * 8;
#pragma unroll
  for (int it = 0; it < 2; ++it) {  // stage W (8 KB)
    int idx = t + it * 256;
    int kr = idx >> 4, c4 = (idx & 15) * 4;
    *reinterpret_cast<float4*>(&sW[kr * 64 + c4]) =
        *reinterpret_cast<const float4*>(&W[kr * 64 + c4]);
  }
  int node = t >> 5, fg = t & 7, way = (t >> 3) & 3;
  float4 z = gather32_core(reinterpret_cast<const float4*>(H), epk, row_start, dinv,
                           n0 + node, fg, way);
  if (way == 0) {
    sZT[fg * 4 + 0][node] = z.x;
    sZT[fg * 4 + 1][node] = z.y;
    sZT[fg * 4 + 2][node] = z.z;
    sZT[fg * 4 + 3][node] = z.w;
  }
  __syncthreads();
  int nd = t >> 5, col = t & 31;
  float a = bias[col], b = bias[col + 32];
#pragma unroll
  for (int k = 0; k < 32; ++k) {
    float zv = sZT[k][nd];
    a = fmaf(zv, sW[k * 64 + col], a);
    b = fmaf(zv, sW[k * 64 + col + 32], b);
  }
  Y[(size_t)(n0 + nd) * 64 + col] = fmaxf(a, 0.f);
  Y[(size_t)(n0 + nd) * 64 + col + 32] = fmaxf(b, 0.f);
}

// ---------------- standalone 4-way gather F=64: 1 wave/node, z3 to global -----------
// fg = lane&15 (16 float4 groups), way = (lane>>4)&3. NN % 4 == 0.
__launch_bounds__(256)
__global__ void k_gath64(const float* __restrict__ H, const int2* __restrict__ epk,
                         const int* __restrict__ row_start, const float* __restrict__ dinv,
                         float* __restrict__ Z) {
  int t = threadIdx.x;
  int n = blockIdx.x * 4 + (t >> 6);
  int fg = t & 15, way = (t >> 4) & 3;
  const float4* H4 = reinterpret_cast<const float4*>(H);
  float4 acc = make_float4(0.f, 0.f, 0.f, 0.f);
  if (way == 0) {
    float dv = dinv[n], s2 = 2.f * dv * dv;
    float4 h = H4[(size_t)n * 16 + fg];
    acc.x = s2 * h.x; acc.y = s2 * h.y; acc.z = s2 * h.z; acc.w = s2 * h.w;
  }
  int end = row_start[n + 1];
  int i = row_start[n] + way;
  for (; i + 4 < end; i += 8) {
    int2 p0 = epk[i], p1 = epk[i + 4];
    float c0f = __int_as_float(p0.y), c1f = __int_as_float(p1.y);
    float4 a = H4[(size_t)p0.x * 16 + fg];
    float4 b = H4[(size_t)p1.x * 16 + fg];
    acc.x = fmaf(c0f, a.x, acc.x); acc.y = fmaf(c0f, a.y, acc.y);
    acc.z = fmaf(c0f, a.z, acc.z); acc.w = fmaf(c0f, a.w, acc.w);
    acc.x = fmaf(c1f, b.x, acc.x); acc.y = fmaf(c1f, b.y, acc.y);
    acc.z = fmaf(c1f, b.z, acc.z); acc.w = fmaf(c1f, b.w, acc.w);
  }
  if (i < end) {
    int2 p = epk[i];
    float cf = __int_as_float(p.y);
    float4 a = H4[(size_t)p.x * 16 + fg];
    acc.x = fmaf(cf, a.x, acc.x); acc.y = fmaf(cf, a.y, acc.y);
    acc.z = fmaf(cf, a.z, acc.z); acc.w = fmaf(cf, a.w, acc.w);
  }
  acc.x += __shfl_xor(acc.x, 16); acc.y += __shfl_xor(acc.y, 16);
  acc.z += __shfl_xor(acc.z, 16); acc.w += __shfl_xor(acc.w, 16);
  acc.x += __shfl_xor(acc.x, 32); acc.y += __shfl_xor(acc.y, 32);
  acc.z += __shfl_xor(acc.z, 32); acc.w += __shfl_xor(acc.w, 32);
  if (way == 0)
    *reinterpret_cast<float4*>(&Z[(size_t)n * 64 + fg * 4]) = acc;
}

// ------- decode: x3 = relu(z3@Wc3+bc3) in LDS, out = c0 + x3@A3 + x2@A2 + x1@A1 -------
__launch_bounds__(256)
__global__ void k_decode(const float* __restrict__ Z3, const float* __restrict__ X2,
                         const float* __restrict__ X1,
                         const float* __restrict__ W3, const float* __restrict__ bc3,
                         const float* __restrict__ Acat, const float* __restrict__ c0,
                         float* __restrict__ out) {
  __shared__ float sZ[32 * 33];     // x-chunk [row][k]
  __shared__ float sX3[32 * 129];   // x3 tile [row][feat]
  __shared__ float sA[32 * 128];    // streamed W3/A chunks [k][col]
  int t = threadIdx.x;
  int n0 = blockIdx.x * 32;
  int rg = t >> 5;   // 0..7 -> rows 4rg..4rg+3
  int cg = t & 31;   // cols 4cg..4cg+3
  int srow = t >> 3, sk4 = (t & 7) * 4;   // staging coords
  int sn = n0 + srow;

  // ---- Phase B: x3 = relu(z3 @ Wc3 + bc3) ----
  float xb[4][4];
  {
    float4 bv = *reinterpret_cast<const float4*>(&bc3[cg * 4]);
#pragma unroll
    for (int r = 0; r < 4; ++r) { xb[r][0] = bv.x; xb[r][1] = bv.y; xb[r][2] = bv.z; xb[r][3] = bv.w; }
  }
  for (int ch = 0; ch < 2; ++ch) {
    __syncthreads();
#pragma unroll
    for (int it = 0; it < 4; ++it) {
      int idx = t + it * 256;
      int kr = idx >> 5, c4 = (idx & 31) * 4;
      *reinterpret_cast<float4*>(&sA[kr * 128 + c4]) =
          *reinterpret_cast<const float4*>(&W3[(ch * 32 + kr) * 128 + c4]);
    }
    {
      float4 v = make_float4(0.f, 0.f, 0.f, 0.f);
      if (sn < NN) v = *reinterpret_cast<const float4*>(&Z3[(size_t)sn * 64 + ch * 32 + sk4]);
      sZ[srow * 33 + sk4 + 0] = v.x;
      sZ[srow * 33 + sk4 + 1] = v.y;
      sZ[srow * 33 + sk4 + 2] = v.z;
      sZ[srow * 33 + sk4 + 3] = v.w;
    }
    __syncthreads();
#pragma unroll
    for (int k = 0; k < 32; ++k) {
      float4 a = *reinterpret_cast<const float4*>(&sA[k * 128 + cg * 4]);
#pragma unroll
      for (int r = 0; r < 4; ++r) {
        float xv = sZ[(rg * 4 + r) * 33 + k];
        xb[r][0] = fmaf(xv, a.x, xb[r][0]); xb[r][1] = fmaf(xv, a.y, xb[r][1]);
        xb[r][2] = fmaf(xv, a.z, xb[r][2]); xb[r][3] = fmaf(xv, a.w, xb[r][3]);
      }
    }
  }
#pragma unroll
  for (int r = 0; r < 4; ++r)
#pragma unroll
    for (int c = 0; c < 4; ++c)
      sX3[(rg * 4 + r) * 129 + cg * 4 + c] = fmaxf(xb[r][c], 0.f);

  // ---- Phase C: out = c0 + x3@A3 + x2@A2 + x1@A1 ----
  float o[4][4];
  {
    float4 cv = *reinterpret_cast<const float4*>(&c0[cg * 4]);
#pragma unroll
    for (int r = 0; r < 4; ++r) { o[r][0] = cv.x; o[r][1] = cv.y; o[r][2] = cv.z; o[r][3] = cv.w; }
  }
  for (int ch = 0; ch < 7; ++ch) {
    __syncthreads();
#pragma unroll
    for (int it = 0; it < 4; ++it) {
      int idx = t + it * 256;
      int kr = idx >> 5, c4 = (idx & 31) * 4;
      *reinterpret_cast<float4*>(&sA[kr * 128 + c4]) =
          *reinterpret_cast<const float4*>(&Acat[(ch * 32 + kr) * 128 + c4]);
    }
    if (ch >= 4) {  // stage x2/x1 chunk
      float4 v = make_float4(0.f, 0.f, 0.f, 0.f);
      if (sn < NN) {
        if (ch < 6) v = *reinterpret_cast<const float4*>(&X2[(size_t)sn * 64 + (ch - 4) * 32 + sk4]);
        else        v = *reinterpret_cast<const float4*>(&X1[(size_t)sn * 32 + sk4]);
      }
      sZ[srow * 33 + sk4 + 0] = v.x;
      sZ[srow * 33 + sk4 + 1] = v.y;
      sZ[srow * 33 + sk4 + 2] = v.z;
      sZ[srow * 33 + sk4 + 3] = v.w;
    }
    __syncthreads();
    const float* xp = (ch < 4) ? &sX3[ch * 32] : &sZ[0];
    int xs = (ch < 4) ? 129 : 33;
#pragma unroll
    for (int k = 0; k < 32; ++k) {
      float4 a = *reinterpret_cast<const float4*>(&sA[k * 128 + cg * 4]);
#pragma unroll
      for (int r = 0; r < 4; ++r) {
        float xv = xp[(rg * 4 + r) * xs + k];
        o[r][0] = fmaf(xv, a.x, o[r][0]); o[r][1] = fmaf(xv, a.y, o[r][1]);
        o[r][2] = fmaf(xv, a.z, o[r][2]); o[r][3] = fmaf(xv, a.w, o[r][3]);
      }
    }
  }
#pragma unroll
  for (int r = 0; r < 4; ++r) {
    int n = n0 + rg * 4 + r;
    if (n < NN)
      *reinterpret_cast<float4*>(&out[(size_t)n * 128 + cg * 4]) =
          make_float4(o[r][0], o[r][1], o[r][2], o[r][3]);
  }
}

extern "C" void kernel_launch(void* const* d_in, const int* in_sizes, int n_in,
                              void* d_out, int out_size, void* d_ws, size_t ws_size,
                              hipStream_t stream) {
  const float* x   = (const float*)d_in[0];
  const int* ei    = (const int*)d_in[1];
  const int* srcv  = ei;
  const int* dstv  = ei + NE;
  const float* w1  = (const float*)d_in[2];
  const float* b1  = (const float*)d_in[3];
  const float* fw1 = (const float*)d_in[4];
  const float* fb1 = (const float*)d_in[5];
  const float* w2  = (const float*)d_in[6];
  const float* b2  = (const float*)d_in[7];
  const float* fw2 = (const float*)d_in[8];
  const float* fb2 = (const float*)d_in[9];
  const float* w3  = (const float*)d_in[10];
  const float* b3  = (const float*)d_in[11];
  const float* fw3 = (const float*)d_in[12];
  const float* fb3 = (const float*)d_in[13];
  const float* wd1 = (const float*)d_in[14];
  const float* bd1 = (const float*)d_in[15];
  const float* wd2 = (const float*)d_in[16];
  const float* bd2 = (const float*)d_in[17];
  const float* wd3 = (const float*)d_in[18];
  const float* bd3 = (const float*)d_in[19];
  const float* ws1 = (const float*)d_in[20];
  const float* bs1 = (const float*)d_in[21];
  const float* ws2 = (const float*)d_in[22];
  const float* bs2 = (const float*)d_in[23];
  const float* wf  = (const float*)d_in[24];
  const float* bf  = (const float*)d_in[25];

  float* fp = (float*)d_ws;
  float* dinv = fp;                  // 50176
  float* h1   = dinv + 50176;        // N*32
  float* x1   = h1 + 1600000;        // N*32
  float* x2   = x1 + 1600000;        // N*64
  float* z3   = x2 + 3200000;        // N*64
  float* Wc2  = z3 + 3200000;        // 2048
  float* Wc3  = Wc2 + 2048;          // 8192
  float* bc1  = Wc3 + 8192;          // 64
  float* bc2  = bc1 + 64;            // 64
  float* bc3  = bc2 + 64;            // 128
  float* G    = bc3 + 128;           // 16384
  float* Hm   = G + 16384;           // 16384
  float* A3   = Hm + 16384;          // 16384 } Acat = A3|A2|A1 contiguous
  float* A2   = A3 + 16384;          // 8192  }
  float* A1   = A2 + 8192;           // 4096  }
  float* c0   = A1 + 4096;           // 256
  int* ip     = (int*)(c0 + 256);
  int2* epk   = (int2*)ip;           // 800000 int2 (8B-aligned)
  int* deg    = ip + 1600000;        // 50176
  int* row_start = deg + 50176;      // 50176 (NN+1 used)
  int* cursor = row_start + 50176;   // 50176
  int* blksum = cursor + 50176;      // 256
  int* blkoff = blksum + 256;        // 256
  float* outp = (float*)d_out;

  // ---- CSR build ----
  hipMemsetAsync(deg, 0, NN * sizeof(int), stream);
  k_hist<<<(NE + 255) / 256, 256, 0, stream>>>(dstv, deg);
  k_blksum<<<NBLK, 256, 0, stream>>>(deg, blksum);
  k_blkscan<<<1, 256, 0, stream>>>(blksum, blkoff);
  k_scan3<<<NBLK, 256, 0, stream>>>(deg, blkoff, row_start, cursor, dinv);
  k_scatter<<<(NE + 255) / 256, 256, 0, stream>>>(srcv, dstv, dinv, cursor, epk);

  // ---- weight composition ----
  k_prep_misc<<<41, 256, 0, stream>>>(w2, fw2, w3, fw3, b1, fw1, fb1, b2, fb2, b3, fb3,
                                      Wc2, Wc3, bc1, bc2, bc3);
  k_prep_G<<<64, 256, 0, stream>>>(wd3, wf, G);
  k_prep_HA1<<<80, 256, 0, stream>>>(wd2, G, ws2, Hm, A1);
  k_prep_A32c0<<<97, 256, 0, stream>>>(wd1, ws1, Hm, G, wf, bd1, bs1, bd2, bs2, bd3, bf,
                                       A3, A2, c0);

  // ---- pipeline ----
  k_gemm1t<<<(NN + 127) / 128, 256, 0, stream>>>(x, w1, h1);
  k_fuse1<<<NN / 8, 256, 0, stream>>>(h1, epk, row_start, dinv, fw1, bc1, x1);
  k_fuse2<<<NN / 8, 256, 0, stream>>>(x1, epk, row_start, dinv, Wc2, bc2, x2);
  k_gath64<<<NN / 4, 256, 0, stream>>>(x2, epk, row_start, dinv, z3);
  k_decode<<<(NN + 31) / 32, 256, 0, stream>>>(z3, x2, x1, Wc3, bc3, A3 /*Acat*/, c0, outp);
}

// Round 6
// 235.767 us; speedup vs baseline: 1.1732x; 1.1732x over previous
//
#include <hip/hip_runtime.h>

#define NN 50000
#define NE 800000
#define NBLK 196  // ceil(NN/256)

typedef _Float16 half8 __attribute__((ext_vector_type(8)));
typedef _Float16 half4 __attribute__((ext_vector_type(4)));
typedef float f32x4v __attribute__((ext_vector_type(4)));

// ---------------- CSR build ----------------
__global__ void k_hist(const int* __restrict__ dst, int* __restrict__ deg) {
  int e = blockIdx.x * 256 + threadIdx.x;
  if (e < NE) atomicAdd(&deg[dst[e]], 1);
}

__global__ void k_blksum(const int* __restrict__ deg, int* __restrict__ blksum) {
  __shared__ int s[256];
  int n = blockIdx.x * 256 + threadIdx.x;
  s[threadIdx.x] = (n < NN) ? deg[n] : 0;
  __syncthreads();
  for (int off = 128; off > 0; off >>= 1) {
    if (threadIdx.x < off) s[threadIdx.x] += s[threadIdx.x + off];
    __syncthreads();
  }
  if (threadIdx.x == 0) blksum[blockIdx.x] = s[0];
}

__global__ void k_blkscan(const int* __restrict__ blksum, int* __restrict__ blkoff) {
  __shared__ int s[256];
  int t = threadIdx.x;
  int v0 = (t < NBLK) ? blksum[t] : 0;
  s[t] = v0;
  __syncthreads();
  for (int off = 1; off < 256; off <<= 1) {
    int v = (t >= off) ? s[t - off] : 0;
    __syncthreads();
    s[t] += v;
    __syncthreads();
  }
  if (t < NBLK) blkoff[t] = s[t] - v0;  // exclusive
}

__global__ void k_scan3(const int* __restrict__ deg, const int* __restrict__ blkoff,
                        int* __restrict__ row_start, int* __restrict__ cursor,
                        float* __restrict__ dinv) {
  __shared__ int s[256];
  int n = blockIdx.x * 256 + threadIdx.x;
  int d = (n < NN) ? deg[n] : 0;
  s[threadIdx.x] = d;
  __syncthreads();
  for (int off = 1; off < 256; off <<= 1) {
    int v = (threadIdx.x >= off) ? s[threadIdx.x - off] : 0;
    __syncthreads();
    s[threadIdx.x] += v;
    __syncthreads();
  }
  if (n < NN) {
    int rs = blkoff[blockIdx.x] + s[threadIdx.x] - d;
    row_start[n] = rs;
    cursor[n] = rs;
    dinv[n] = rsqrtf((float)d + 2.0f);
  }
  if (n == 0) row_start[NN] = NE;
}

__global__ void k_scatter(const int* __restrict__ srcv, const int* __restrict__ dstv,
                          const float* __restrict__ dinv, int* __restrict__ cursor,
                          int2* __restrict__ epk) {
  int e = blockIdx.x * 256 + threadIdx.x;
  if (e >= NE) return;
  int s = srcv[e], d = dstv[e];
  int pos = atomicAdd(&cursor[d], 1);
  epk[pos] = make_int2(s, __float_as_int(dinv[s] * dinv[d]));
}

// ---------------- weight composition (tiny) ----------------
__global__ void k_prep_misc(const float* __restrict__ w2, const float* __restrict__ fw2,
                            const float* __restrict__ w3, const float* __restrict__ fw3,
                            const float* __restrict__ b1, const float* __restrict__ fw1,
                            const float* __restrict__ fb1,
                            const float* __restrict__ b2, const float* __restrict__ fb2,
                            const float* __restrict__ b3, const float* __restrict__ fb3,
                            float* __restrict__ Wc2, float* __restrict__ Wc3,
                            float* __restrict__ bc1, float* __restrict__ bc2,
                            float* __restrict__ bc3) {
  int id = blockIdx.x * 256 + threadIdx.x;
  if (id < 2048) {                       // Wc2 [32,64]
    int c = id >> 6, k = id & 63;
    float s = 0.f;
    for (int j = 0; j < 64; ++j) s = fmaf(w2[c * 64 + j], fw2[j * 64 + k], s);
    Wc2[id] = s;
  } else if (id < 10240) {               // Wc3 [64,128]
    int idx = id - 2048;
    int c = idx >> 7, k = idx & 127;
    float s = 0.f;
    for (int j = 0; j < 128; ++j) s = fmaf(w3[c * 128 + j], fw3[j * 128 + k], s);
    Wc3[idx] = s;
  } else if (id < 10272) {               // bc1 [32]
    int k = id - 10240;
    float s = fb1[k];
    for (int j = 0; j < 32; ++j) s = fmaf(b1[j], fw1[j * 32 + k], s);
    bc1[k] = s;
  } else if (id < 10336) {               // bc2 [64]
    int k = id - 10272;
    float s = fb2[k];
    for (int j = 0; j < 64; ++j) s = fmaf(b2[j], fw2[j * 64 + k], s);
    bc2[k] = s;
  } else if (id < 10464) {               // bc3 [128]
    int k = id - 10336;
    float s = fb3[k];
    for (int j = 0; j < 128; ++j) s = fmaf(b3[j], fw3[j * 128 + k], s);
    bc3[k] = s;
  }
}

__global__ void k_prep_G(const float* __restrict__ wd3, const float* __restrict__ wf,
                         float* __restrict__ G) {
  int id = blockIdx.x * 256 + threadIdx.x;
  if (id >= 16384) return;
  int k = id & 127, r = id >> 7;
  int c = r >> 2, l = r & 3;
  float s = 0.f;
  for (int o = 0; o < 32; ++o) {
    s = fmaf(wd3[c * 64 + o * 2 + 0], wf[(o * 8 + 2 * l + 0) * 128 + k], s);
    s = fmaf(wd3[c * 64 + o * 2 + 1], wf[(o * 8 + 2 * l + 1) * 128 + k], s);
  }
  G[r * 128 + k] = s;
}

__global__ void k_prep_HA1(const float* __restrict__ wd2, const float* __restrict__ G,
                           const float* __restrict__ ws2,
                           float* __restrict__ Hm, float* __restrict__ A1) {
  int id = blockIdx.x * 256 + threadIdx.x;
  if (id < 16384) {
    int k = id & 127, r = id >> 7;
    int c = r >> 1, l = r & 1;
    float s = 0.f;
    for (int o = 0; o < 32; ++o) {
      s = fmaf(wd2[c * 64 + o * 2 + 0], G[(o * 4 + 2 * l + 0) * 128 + k], s);
      s = fmaf(wd2[c * 64 + o * 2 + 1], G[(o * 4 + 2 * l + 1) * 128 + k], s);
    }
    Hm[r * 128 + k] = s;
  } else if (id < 16384 + 4096) {
    int idx = id - 16384;
    int k = idx & 127, c = idx >> 7;   // c < 32
    float s = 0.f;
    for (int o = 0; o < 32; ++o) {
      float g = G[(4 * o) * 128 + k] + G[(4 * o + 1) * 128 + k] +
                G[(4 * o + 2) * 128 + k] + G[(4 * o + 3) * 128 + k];
      s = fmaf(ws2[c * 32 + o], g, s);
    }
    A1[c * 128 + k] = s;
  }
}

__global__ void k_prep_A32c0(const float* __restrict__ wd1, const float* __restrict__ ws1,
                             const float* __restrict__ Hm, const float* __restrict__ G,
                             const float* __restrict__ wf,
                             const float* __restrict__ bd1, const float* __restrict__ bs1,
                             const float* __restrict__ bd2, const float* __restrict__ bs2,
                             const float* __restrict__ bd3, const float* __restrict__ bf,
                             float* __restrict__ A3, float* __restrict__ A2,
                             float* __restrict__ c0) {
  int id = blockIdx.x * 256 + threadIdx.x;
  if (id < 16384) {
    int k = id & 127, c = id >> 7;
    float s = 0.f;
    for (int j = 0; j < 128; ++j) s = fmaf(wd1[c * 128 + j], Hm[j * 128 + k], s);
    A3[c * 128 + k] = s;
  } else if (id < 16384 + 8192) {
    int idx = id - 16384;
    int k = idx & 127, c = idx >> 7;   // c < 64
    float s = 0.f;
    for (int o = 0; o < 64; ++o)
      s = fmaf(ws1[c * 64 + o], Hm[(2 * o) * 128 + k] + Hm[(2 * o + 1) * 128 + k], s);
    A2[c * 128 + k] = s;
  } else if (id < 16384 + 8192 + 128) {
    int k = id - 16384 - 8192;
    float s = bf[k];
    for (int o = 0; o < 64; ++o) {
      float b = bd1[o] + bs1[o];
      s = fmaf(b, Hm[(o * 2) * 128 + k] + Hm[(o * 2 + 1) * 128 + k], s);
    }
    for (int o = 0; o < 32; ++o) {
      float b = bd2[o] + bs2[o];
      float g = G[(o * 4) * 128 + k] + G[(o * 4 + 1) * 128 + k] +
                G[(o * 4 + 2) * 128 + k] + G[(o * 4 + 3) * 128 + k];
      s = fmaf(b, g, s);
    }
    for (int o = 0; o < 32; ++o) {
      float w8 = 0.f;
      for (int j = 0; j < 8; ++j) w8 += wf[(o * 8 + j) * 128 + k];
      s = fmaf(bd3[o], w8, s);
    }
    c0[k] = s;
  }
}

// -------- pack B fragments (f16) for mfma_f32_16x16x32_f16 --------
// frag (kb,nb): lane l, slot j  ->  B[kb*32 + (l>>4)*8 + j][nb*16 + (l&15)]
// W3pk: 2 kb x 8 nb;  Apk: 7 kb x 8 nb over Acat[224][128]
__global__ void k_prep_pack(const float* __restrict__ Wc3, const float* __restrict__ Acat,
                            _Float16* __restrict__ W3pk, _Float16* __restrict__ Apk) {
  int id = blockIdx.x * 256 + threadIdx.x;
  if (id < 1024) {
    int l = id & 63, nb = (id >> 6) & 7, kb = id >> 9;
    int kbase = kb * 32 + ((l >> 4) << 3);
    int col = nb * 16 + (l & 15);
#pragma unroll
    for (int j = 0; j < 8; ++j)
      W3pk[id * 8 + j] = (_Float16)Wc3[(kbase + j) * 128 + col];
  } else if (id < 1024 + 3584) {
    int idx = id - 1024;
    int l = idx & 63, nb = (idx >> 6) & 7, kb = idx >> 9;
    int kbase = kb * 32 + ((l >> 4) << 3);
    int col = nb * 16 + (l & 15);
#pragma unroll
    for (int j = 0; j < 8; ++j)
      Apk[idx * 8 + j] = (_Float16)Acat[(kbase + j) * 128 + col];
  }
}

// ---------------- layer-1 projection: h1 = x @ w1 (128->32), register-tiled ----------
__launch_bounds__(256)
__global__ void k_gemm1t(const float* __restrict__ X, const float* __restrict__ W,
                         float* __restrict__ Y) {
  __shared__ float sW[128 * 32];
  __shared__ float sXc[128 * 33];
  int t = threadIdx.x;
  int n0 = blockIdx.x * 128;
#pragma unroll
  for (int it = 0; it < 4; ++it) {          // stage full W (16 KB)
    int idx = t + it * 256;                  // 1024 float4 slots
    int kr = idx >> 3, c4 = (idx & 7) * 4;
    *reinterpret_cast<float4*>(&sW[kr * 32 + c4]) =
        *reinterpret_cast<const float4*>(&W[kr * 32 + c4]);
  }
  int rg = t >> 3;   // 0..31 -> rows 4rg..4rg+3
  int cg = t & 7;    // cols 4cg..4cg+3
  float acc[4][4];
#pragma unroll
  for (int r = 0; r < 4; ++r)
#pragma unroll
    for (int c = 0; c < 4; ++c) acc[r][c] = 0.f;

  for (int ch = 0; ch < 4; ++ch) {
    __syncthreads();
#pragma unroll
    for (int it = 0; it < 4; ++it) {        // stage X chunk [128 rows][32 k]
      int idx = t + it * 256;
      int row = idx & 127, k4 = (idx >> 7) * 4;
      int n = n0 + row;
      float4 v = make_float4(0.f, 0.f, 0.f, 0.f);
      if (n < NN) v = *reinterpret_cast<const float4*>(&X[(size_t)n * 128 + ch * 32 + k4]);
      sXc[row * 33 + k4 + 0] = v.x;
      sXc[row * 33 + k4 + 1] = v.y;
      sXc[row * 33 + k4 + 2] = v.z;
      sXc[row * 33 + k4 + 3] = v.w;
    }
    __syncthreads();
#pragma unroll
    for (int k = 0; k < 32; ++k) {
      float4 w = *reinterpret_cast<const float4*>(&sW[(ch * 32 + k) * 32 + cg * 4]);
#pragma unroll
      for (int r = 0; r < 4; ++r) {
        float xv = sXc[(rg * 4 + r) * 33 + k];
        acc[r][0] = fmaf(xv, w.x, acc[r][0]);
        acc[r][1] = fmaf(xv, w.y, acc[r][1]);
        acc[r][2] = fmaf(xv, w.z, acc[r][2]);
        acc[r][3] = fmaf(xv, w.w, acc[r][3]);
      }
    }
  }
#pragma unroll
  for (int r = 0; r < 4; ++r) {
    int n = n0 + rg * 4 + r;
    if (n < NN)
      *reinterpret_cast<float4*>(&Y[(size_t)n * 32 + cg * 4]) =
          make_float4(acc[r][0], acc[r][1], acc[r][2], acc[r][3]);
  }
}

// ---- 4-way gather core for F=32: 32 lanes/node (fg=lane&7, way=(lane>>3)&3) ----
__device__ inline float4 gather32_core(const float4* __restrict__ H4,
                                       const int2* __restrict__ epk,
                                       const int* __restrict__ row_start,
                                       const float* __restrict__ dinv,
                                       int n, int fg, int way) {
  float4 acc = make_float4(0.f, 0.f, 0.f, 0.f);
  if (way == 0) {
    float dv = dinv[n], s2 = 2.f * dv * dv;
    float4 h = H4[(size_t)n * 8 + fg];
    acc.x = s2 * h.x; acc.y = s2 * h.y; acc.z = s2 * h.z; acc.w = s2 * h.w;
  }
  int end = row_start[n + 1];
  int i = row_start[n] + way;
  for (; i + 4 < end; i += 8) {
    int2 p0 = epk[i], p1 = epk[i + 4];
    float c0f = __int_as_float(p0.y), c1f = __int_as_float(p1.y);
    float4 a = H4[(size_t)p0.x * 8 + fg];
    float4 b = H4[(size_t)p1.x * 8 + fg];
    acc.x = fmaf(c0f, a.x, acc.x); acc.y = fmaf(c0f, a.y, acc.y);
    acc.z = fmaf(c0f, a.z, acc.z); acc.w = fmaf(c0f, a.w, acc.w);
    acc.x = fmaf(c1f, b.x, acc.x); acc.y = fmaf(c1f, b.y, acc.y);
    acc.z = fmaf(c1f, b.z, acc.z); acc.w = fmaf(c1f, b.w, acc.w);
  }
  if (i < end) {
    int2 p = epk[i];
    float cf = __int_as_float(p.y);
    float4 a = H4[(size_t)p.x * 8 + fg];
    acc.x = fmaf(cf, a.x, acc.x); acc.y = fmaf(cf, a.y, acc.y);
    acc.z = fmaf(cf, a.z, acc.z); acc.w = fmaf(cf, a.w, acc.w);
  }
  // butterfly reduce over 4 ways (masks 8,16 within the 32-lane node group)
  acc.x += __shfl_xor(acc.x, 8);  acc.y += __shfl_xor(acc.y, 8);
  acc.z += __shfl_xor(acc.z, 8);  acc.w += __shfl_xor(acc.w, 8);
  acc.x += __shfl_xor(acc.x, 16); acc.y += __shfl_xor(acc.y, 16);
  acc.z += __shfl_xor(acc.z, 16); acc.w += __shfl_xor(acc.w, 16);
  return acc;
}

// ---------------- fused 4-way gather(F=32) + GEMM 32->32 + relu ----------------
__launch_bounds__(256)
__global__ void k_fuse1(const float* __restrict__ H, const int2* __restrict__ epk,
                        const int* __restrict__ row_start, const float* __restrict__ dinv,
                        const float* __restrict__ W, const float* __restrict__ bias,
                        float* __restrict__ Y) {
  __shared__ float sZT[32][9];   // [feat][node]
  __shared__ float sW[32 * 32];
  int t = threadIdx.x;
  int n0 = blockIdx.x * 8;
  {  // stage W (4 KB)
    int kr = t >> 3, c4 = (t & 7) * 4;
    *reinterpret_cast<float4*>(&sW[kr * 32 + c4]) =
        *reinterpret_cast<const float4*>(&W[kr * 32 + c4]);
  }
  int node = t >> 5, fg = t & 7, way = (t >> 3) & 3;
  float4 z = gather32_core(reinterpret_cast<const float4*>(H), epk, row_start, dinv,
                           n0 + node, fg, way);
  if (way == 0) {
    sZT[fg * 4 + 0][node] = z.x;
    sZT[fg * 4 + 1][node] = z.y;
    sZT[fg * 4 + 2][node] = z.z;
    sZT[fg * 4 + 3][node] = z.w;
  }
  __syncthreads();
  int nd = t >> 5, col = t & 31;
  float a = bias[col];
#pragma unroll
  for (int k = 0; k < 32; ++k) a = fmaf(sZT[k][nd], sW[k * 32 + col], a);
  Y[(size_t)(n0 + nd) * 32 + col] = fmaxf(a, 0.f);
}

// ---------------- fused 4-way gather(F=32) + GEMM 32->64 + relu ----------------
__launch_bounds__(256)
__global__ void k_fuse2(const float* __restrict__ H, const int2* __restrict__ epk,
                        const int* __restrict__ row_start, const float* __restrict__ dinv,
                        const float* __restrict__ W, const float* __restrict__ bias,
                        float* __restrict__ Y) {
  __shared__ float sZT[32][9];
  __shared__ float sW[32 * 64];
  int t = threadIdx.x;
  int n0 = blockIdx.x * 8;
#pragma unroll
  for (int it = 0; it < 2; ++it) {  // stage W (8 KB)
    int idx = t + it * 256;
    int kr = idx >> 4, c4 = (idx & 15) * 4;
    *reinterpret_cast<float4*>(&sW[kr * 64 + c4]) =
        *reinterpret_cast<const float4*>(&W[kr * 64 + c4]);
  }
  int node = t >> 5, fg = t & 7, way = (t >> 3) & 3;
  float4 z = gather32_core(reinterpret_cast<const float4*>(H), epk, row_start, dinv,
                           n0 + node, fg, way);
  if (way == 0) {
    sZT[fg * 4 + 0][node] = z.x;
    sZT[fg * 4 + 1][node] = z.y;
    sZT[fg * 4 + 2][node] = z.z;
    sZT[fg * 4 + 3][node] = z.w;
  }
  __syncthreads();
  int nd = t >> 5, col = t & 31;
  float a = bias[col], b = bias[col + 32];
#pragma unroll
  for (int k = 0; k < 32; ++k) {
    float zv = sZT[k][nd];
    a = fmaf(zv, sW[k * 64 + col], a);
    b = fmaf(zv, sW[k * 64 + col + 32], b);
  }
  Y[(size_t)(n0 + nd) * 64 + col] = fmaxf(a, 0.f);
  Y[(size_t)(n0 + nd) * 64 + col + 32] = fmaxf(b, 0.f);
}

// ------- standalone 4-way gather F=64: 1 wave/node, z3 written as f16 -------
__launch_bounds__(256)
__global__ void k_gath64(const float* __restrict__ H, const int2* __restrict__ epk,
                         const int* __restrict__ row_start, const float* __restrict__ dinv,
                         _Float16* __restrict__ Zh) {
  int t = threadIdx.x;
  int n = blockIdx.x * 4 + (t >> 6);
  int fg = t & 15, way = (t >> 4) & 3;
  const float4* H4 = reinterpret_cast<const float4*>(H);
  float4 acc = make_float4(0.f, 0.f, 0.f, 0.f);
  if (way == 0) {
    float dv = dinv[n], s2 = 2.f * dv * dv;
    float4 h = H4[(size_t)n * 16 + fg];
    acc.x = s2 * h.x; acc.y = s2 * h.y; acc.z = s2 * h.z; acc.w = s2 * h.w;
  }
  int end = row_start[n + 1];
  int i = row_start[n] + way;
  for (; i + 4 < end; i += 8) {
    int2 p0 = epk[i], p1 = epk[i + 4];
    float c0f = __int_as_float(p0.y), c1f = __int_as_float(p1.y);
    float4 a = H4[(size_t)p0.x * 16 + fg];
    float4 b = H4[(size_t)p1.x * 16 + fg];
    acc.x = fmaf(c0f, a.x, acc.x); acc.y = fmaf(c0f, a.y, acc.y);
    acc.z = fmaf(c0f, a.z, acc.z); acc.w = fmaf(c0f, a.w, acc.w);
    acc.x = fmaf(c1f, b.x, acc.x); acc.y = fmaf(c1f, b.y, acc.y);
    acc.z = fmaf(c1f, b.z, acc.z); acc.w = fmaf(c1f, b.w, acc.w);
  }
  if (i < end) {
    int2 p = epk[i];
    float cf = __int_as_float(p.y);
    float4 a = H4[(size_t)p.x * 16 + fg];
    acc.x = fmaf(cf, a.x, acc.x); acc.y = fmaf(cf, a.y, acc.y);
    acc.z = fmaf(cf, a.z, acc.z); acc.w = fmaf(cf, a.w, acc.w);
  }
  acc.x += __shfl_xor(acc.x, 16); acc.y += __shfl_xor(acc.y, 16);
  acc.z += __shfl_xor(acc.z, 16); acc.w += __shfl_xor(acc.w, 16);
  acc.x += __shfl_xor(acc.x, 32); acc.y += __shfl_xor(acc.y, 32);
  acc.z += __shfl_xor(acc.z, 32); acc.w += __shfl_xor(acc.w, 32);
  if (way == 0) {
    half4 hv;
    hv[0] = (_Float16)acc.x; hv[1] = (_Float16)acc.y;
    hv[2] = (_Float16)acc.z; hv[3] = (_Float16)acc.w;
    *reinterpret_cast<half4*>(Zh + (size_t)n * 64 + fg * 4) = hv;
  }
}

// ---- convert 8 f32 -> half8 fragment ----
__device__ inline half8 cvt8(const float* __restrict__ p) {
  float4 u = *reinterpret_cast<const float4*>(p);
  float4 v = *reinterpret_cast<const float4*>(p + 4);
  half8 a;
  a[0] = (_Float16)u.x; a[1] = (_Float16)u.y; a[2] = (_Float16)u.z; a[3] = (_Float16)u.w;
  a[4] = (_Float16)v.x; a[5] = (_Float16)v.y; a[6] = (_Float16)v.z; a[7] = (_Float16)v.w;
  return a;
}

// ------- MFMA decode: x3 = relu(z3@Wc3+bc3); out = c0 + [x3|x2|x1] @ Acat -------
// 4 waves/block, 64 rows x 128 cols. Per wave: 16-row strip, 8 N-frags f32x4.
// A-frags: z3h (f16 global), x3 (wave-private LDS), x2/x1 (f32 global + cvt).
// B-frags: prepacked per-lane order, direct L2-broadcast loads (no barriers in loops).
__launch_bounds__(256)
__global__ void k_decode(const _Float16* __restrict__ z3h, const float* __restrict__ X2,
                         const float* __restrict__ X1,
                         const half8* __restrict__ W3pk, const half8* __restrict__ Apk,
                         const float* __restrict__ bc3, const float* __restrict__ c0,
                         float* __restrict__ out) {
  __shared__ _Float16 sX3[4][16][136];  // per-wave x3 tile, padded row (+8) for banks
  int t = threadIdx.x;
  int w = t >> 6, l = t & 63;
  int m16 = l & 15, g = l >> 4;          // A-row in tile, k-group
  int n0 = blockIdx.x * 64 + w * 16;
  int nrow = n0 + m16;                   // row this lane loads A from (< 50048 alloc)

  f32x4v acc[8];
  // ---- Phase B: x3 = relu(z3 @ Wc3 + bc3), K=64 ----
#pragma unroll
  for (int nb = 0; nb < 8; ++nb) {
    float bv = bc3[nb * 16 + m16];
    acc[nb] = (f32x4v){bv, bv, bv, bv};
  }
#pragma unroll
  for (int kb = 0; kb < 2; ++kb) {
    half8 a = *reinterpret_cast<const half8*>(z3h + (size_t)nrow * 64 + kb * 32 + g * 8);
#pragma unroll
    for (int nb = 0; nb < 8; ++nb) {
      half8 b = W3pk[(kb * 8 + nb) * 64 + l];
      acc[nb] = __builtin_amdgcn_mfma_f32_16x16x32_f16(a, b, acc[nb], 0, 0, 0);
    }
  }
  // D layout: col = l&15, row = g*4 + r  -> write x3[row][col] to wave tile
#pragma unroll
  for (int nb = 0; nb < 8; ++nb)
#pragma unroll
    for (int r = 0; r < 4; ++r)
      sX3[w][g * 4 + r][nb * 16 + m16] = (_Float16)fmaxf(acc[nb][r], 0.0f);
  __syncthreads();  // cross-lane LDS visibility (conservative; waves independent)

  // ---- Phase C: out = c0 + [x3|x2|x1] @ Acat, K=224 (7 k-blocks) ----
#pragma unroll
  for (int nb = 0; nb < 8; ++nb) {
    float cv = c0[nb * 16 + m16];
    acc[nb] = (f32x4v){cv, cv, cv, cv};
  }
#pragma unroll
  for (int kb = 0; kb < 7; ++kb) {
    half8 a;
    if (kb < 4)
      a = *reinterpret_cast<const half8*>(&sX3[w][m16][kb * 32 + g * 8]);
    else if (kb < 6)
      a = cvt8(X2 + (size_t)nrow * 64 + (kb - 4) * 32 + g * 8);
    else
      a = cvt8(X1 + (size_t)nrow * 32 + g * 8);
#pragma unroll
    for (int nb = 0; nb < 8; ++nb) {
      half8 b = Apk[(kb * 8 + nb) * 64 + l];
      acc[nb] = __builtin_amdgcn_mfma_f32_16x16x32_f16(a, b, acc[nb], 0, 0, 0);
    }
  }
  // store: out[n0 + g*4 + r][nb*16 + m16]
#pragma unroll
  for (int nb = 0; nb < 8; ++nb)
#pragma unroll
    for (int r = 0; r < 4; ++r) {
      int n = n0 + g * 4 + r;
      if (n < NN) out[(size_t)n * 128 + nb * 16 + m16] = acc[nb][r];
    }
}

extern "C" void kernel_launch(void* const* d_in, const int* in_sizes, int n_in,
                              void* d_out, int out_size, void* d_ws, size_t ws_size,
                              hipStream_t stream) {
  const float* x   = (const float*)d_in[0];
  const int* ei    = (const int*)d_in[1];
  const int* srcv  = ei;
  const int* dstv  = ei + NE;
  const float* w1  = (const float*)d_in[2];
  const float* b1  = (const float*)d_in[3];
  const float* fw1 = (const float*)d_in[4];
  const float* fb1 = (const float*)d_in[5];
  const float* w2  = (const float*)d_in[6];
  const float* b2  = (const float*)d_in[7];
  const float* fw2 = (const float*)d_in[8];
  const float* fb2 = (const float*)d_in[9];
  const float* w3  = (const float*)d_in[10];
  const float* b3  = (const float*)d_in[11];
  const float* fw3 = (const float*)d_in[12];
  const float* fb3 = (const float*)d_in[13];
  const float* wd1 = (const float*)d_in[14];
  const float* bd1 = (const float*)d_in[15];
  const float* wd2 = (const float*)d_in[16];
  const float* bd2 = (const float*)d_in[17];
  const float* wd3 = (const float*)d_in[18];
  const float* bd3 = (const float*)d_in[19];
  const float* ws1 = (const float*)d_in[20];
  const float* bs1 = (const float*)d_in[21];
  const float* ws2 = (const float*)d_in[22];
  const float* bs2 = (const float*)d_in[23];
  const float* wf  = (const float*)d_in[24];
  const float* bf  = (const float*)d_in[25];

  float* fp = (float*)d_ws;
  float* dinv = fp;                  // 50176
  float* h1   = dinv + 50176;        // 50048*32 f32; later overlaid by z3h (f16, 50048*64)
  float* x1   = h1 + 1601536;        // 50048*32
  float* x2   = x1 + 1601536;        // 50048*64
  float* Wc2  = x2 + 3203072;        // 2048
  float* Wc3  = Wc2 + 2048;          // 8192
  float* bc1  = Wc3 + 8192;          // 64
  float* bc2  = bc1 + 64;            // 64
  float* bc3  = bc2 + 64;            // 128
  float* G    = bc3 + 128;           // 16384
  float* Hm   = G + 16384;           // 16384
  float* A3   = Hm + 16384;          // 16384 } Acat = A3|A2|A1 contiguous [224][128]
  float* A2   = A3 + 16384;          // 8192  }
  float* A1   = A2 + 8192;           // 4096  }
  float* c0   = A1 + 4096;           // 256
  _Float16* W3pk = (_Float16*)(c0 + 256);   // 8192 halves (2*8*64*8)
  _Float16* Apk  = W3pk + 8192;             // 28672 halves (7*8*64*8)
  int* ip     = (int*)(Apk + 28672);
  int2* epk   = (int2*)ip;           // 800000 int2
  int* deg    = ip + 1600000;        // 50176
  int* row_start = deg + 50176;      // 50176 (NN+1 used)
  int* cursor = row_start + 50176;   // 50176
  int* blksum = cursor + 50176;      // 256
  int* blkoff = blksum + 256;        // 256

  _Float16* z3h = (_Float16*)h1;     // overlay: h1 dead after k_fuse1
  float* outp = (float*)d_out;

  // ---- CSR build ----
  hipMemsetAsync(deg, 0, NN * sizeof(int), stream);
  k_hist<<<(NE + 255) / 256, 256, 0, stream>>>(dstv, deg);
  k_blksum<<<NBLK, 256, 0, stream>>>(deg, blksum);
  k_blkscan<<<1, 256, 0, stream>>>(blksum, blkoff);
  k_scan3<<<NBLK, 256, 0, stream>>>(deg, blkoff, row_start, cursor, dinv);
  k_scatter<<<(NE + 255) / 256, 256, 0, stream>>>(srcv, dstv, dinv, cursor, epk);

  // ---- weight composition ----
  k_prep_misc<<<41, 256, 0, stream>>>(w2, fw2, w3, fw3, b1, fw1, fb1, b2, fb2, b3, fb3,
                                      Wc2, Wc3, bc1, bc2, bc3);
  k_prep_G<<<64, 256, 0, stream>>>(wd3, wf, G);
  k_prep_HA1<<<80, 256, 0, stream>>>(wd2, G, ws2, Hm, A1);
  k_prep_A32c0<<<97, 256, 0, stream>>>(wd1, ws1, Hm, G, wf, bd1, bs1, bd2, bs2, bd3, bf,
                                       A3, A2, c0);
  k_prep_pack<<<18, 256, 0, stream>>>(Wc3, A3 /*Acat*/, W3pk, Apk);

  // ---- pipeline ----
  k_gemm1t<<<(NN + 127) / 128, 256, 0, stream>>>(x, w1, h1);
  k_fuse1<<<NN / 8, 256, 0, stream>>>(h1, epk, row_start, dinv, fw1, bc1, x1);
  k_fuse2<<<NN / 8, 256, 0, stream>>>(x1, epk, row_start, dinv, Wc2, bc2, x2);
  k_gath64<<<NN / 4, 256, 0, stream>>>(x2, epk, row_start, dinv, z3h);
  k_decode<<<(NN + 63) / 64, 256, 0, stream>>>(z3h, x2, x1, (const half8*)W3pk,
                                               (const half8*)Apk, bc3, c0, outp);
}